// Round 1
// baseline (380.920 us; speedup 1.0000x reference)
//
#include <hip/hip_runtime.h>

#define C_DIM 8192
#define BLOCK 256
#define PER_THREAD 32              // C_DIM / BLOCK
#define NVEC 8                     // PER_THREAD / 4 float4 loads per thread

// strict ordering matching jax.lax.top_k: higher value wins, ties -> lower index
__device__ __forceinline__ bool better(float a, int ia, float b, int ib) {
    return (a > b) || (a == b && ia < ib);
}

// insert (x,j) into descending-sorted 4-list
__device__ __forceinline__ void insert4(float v[4], int id[4], float x, int j) {
    if (better(x, j, v[3], id[3])) {
        v[3] = x; id[3] = j;
        if (better(v[3], id[3], v[2], id[2])) { float tv = v[2]; int ti = id[2]; v[2] = v[3]; id[2] = id[3]; v[3] = tv; id[3] = ti; }
        if (better(v[2], id[2], v[1], id[1])) { float tv = v[1]; int ti = id[1]; v[1] = v[2]; id[1] = id[2]; v[2] = tv; id[2] = ti; }
        if (better(v[1], id[1], v[0], id[0])) { float tv = v[0]; int ti = id[0]; v[0] = v[1]; id[0] = id[1]; v[1] = tv; id[1] = ti; }
    }
}

__global__ __launch_bounds__(BLOCK) void row_loss_kernel(const float* __restrict__ preds,
                                                         const int* __restrict__ targets,
                                                         float* __restrict__ row_loss) {
    const int row = blockIdx.x;
    const int tid = threadIdx.x;
    const int lane = tid & 63;
    const int wid = tid >> 6;

    const float4* rp = (const float4*)(preds + (size_t)row * C_DIM);
    const int tgt = targets[row];

    __shared__ float s_xgt;
    __shared__ float s_m[4], s_s[4], s_l[4];
    __shared__ float s_tv[16];
    __shared__ int   s_ti[16];

    float r[PER_THREAD];
    float lmax = -INFINITY;
    float lsum = 0.0f;
    float tv[4] = { -INFINITY, -INFINITY, -INFINITY, -INFINITY };
    int   ti[4] = { 0x7FFFFFFF, 0x7FFFFFFF, 0x7FFFFFFF, 0x7FFFFFFF };

    // Pass 1: stream row into registers; local max / sum / top-4 / gt capture
#pragma unroll
    for (int v = 0; v < NVEC; ++v) {
        float4 f = rp[v * BLOCK + tid];
        const int jb = (v * BLOCK + tid) * 4;
        float e0 = f.x, e1 = f.y, e2 = f.z, e3 = f.w;
        r[v * 4 + 0] = e0; r[v * 4 + 1] = e1; r[v * 4 + 2] = e2; r[v * 4 + 3] = e3;
        lsum += e0 + e1 + e2 + e3;
        lmax = fmaxf(fmaxf(lmax, fmaxf(e0, e1)), fmaxf(e2, e3));
        insert4(tv, ti, e0, jb + 0);
        insert4(tv, ti, e1, jb + 1);
        insert4(tv, ti, e2, jb + 2);
        insert4(tv, ti, e3, jb + 3);
        if (jb + 0 == tgt) s_xgt = e0;
        if (jb + 1 == tgt) s_xgt = e1;
        if (jb + 2 == tgt) s_xgt = e2;
        if (jb + 3 == tgt) s_xgt = e3;
    }

    // Wave-level reductions (64 lanes, butterfly)
    float wm = lmax, wsum = lsum;
#pragma unroll
    for (int o = 32; o; o >>= 1) {
        wm = fmaxf(wm, __shfl_xor(wm, o));
        wsum += __shfl_xor(wsum, o);
    }
#pragma unroll
    for (int o = 32; o; o >>= 1) {
        float ov[4]; int oi[4];
#pragma unroll
        for (int k = 0; k < 4; ++k) { ov[k] = __shfl_xor(tv[k], o); oi[k] = __shfl_xor(ti[k], o); }
#pragma unroll
        for (int k = 0; k < 4; ++k) insert4(tv, ti, ov[k], oi[k]);
    }

    if (lane == 0) {
        s_m[wid] = wm;
        s_s[wid] = wsum;
#pragma unroll
        for (int k = 0; k < 4; ++k) { s_tv[wid * 4 + k] = tv[k]; s_ti[wid * 4 + k] = ti[k]; }
    }
    __syncthreads();

    const float m = fmaxf(fmaxf(s_m[0], s_m[1]), fmaxf(s_m[2], s_m[3]));

    // Pass 2: sum of exp(x - m) from registers
    float le = 0.0f;
#pragma unroll
    for (int k = 0; k < PER_THREAD; ++k) le += __expf(r[k] - m);
#pragma unroll
    for (int o = 32; o; o >>= 1) le += __shfl_xor(le, o);
    if (lane == 0) s_l[wid] = le;
    __syncthreads();

    if (tid == 0) {
        const float Sx = s_s[0] + s_s[1] + s_s[2] + s_s[3];
        const float l  = s_l[0] + s_l[1] + s_l[2] + s_l[3];

        // merge the 4 per-wave top-4 lists
        float fv[4]; int fi[4];
#pragma unroll
        for (int k = 0; k < 4; ++k) { fv[k] = s_tv[k]; fi[k] = s_ti[k]; }
        for (int w = 1; w < 4; ++w)
#pragma unroll
            for (int k = 0; k < 4; ++k) insert4(fv, fi, s_tv[w * 4 + k], s_ti[w * 4 + k]);

        const float logZ  = m + __logf(l);
        const float lp_gt = s_xgt - logZ;

        // first 3 non-gt entries of top-4 (skip exclusion compares against row index,
        // matching the reference's `rows`)
        float skip_x = 0.0f;
        int cnt = 0;
        for (int k = 0; k < 4; ++k) {
            if (fi[k] != row && cnt < 3) { skip_x += fv[k]; ++cnt; }
        }

        const float S_lp    = Sx - (float)C_DIM * logZ;
        const float skip_lp = skip_x - 3.0f * logZ;
        const float eps     = 0.1f / (float)(C_DIM - 1);

        row_loss[row] = -(0.9f * lp_gt + eps * (S_lp - lp_gt - skip_lp));
    }
}

__global__ __launch_bounds__(BLOCK) void mean_reduce_kernel(const float* __restrict__ row_loss,
                                                            float* __restrict__ out) {
    const int tid = threadIdx.x;
    float s = 0.0f;
    for (int i = tid; i < C_DIM; i += BLOCK) s += row_loss[i];
#pragma unroll
    for (int o = 32; o; o >>= 1) s += __shfl_xor(s, o);
    __shared__ float sm[4];
    if ((tid & 63) == 0) sm[tid >> 6] = s;
    __syncthreads();
    if (tid == 0) out[0] = (sm[0] + sm[1] + sm[2] + sm[3]) / (float)C_DIM;
}

extern "C" void kernel_launch(void* const* d_in, const int* in_sizes, int n_in,
                              void* d_out, int out_size, void* d_ws, size_t ws_size,
                              hipStream_t stream) {
    const float* preds   = (const float*)d_in[0];
    const int*   targets = (const int*)d_in[1];
    float*       out     = (float*)d_out;
    float*       ws      = (float*)d_ws;   // 8192 floats of row losses

    row_loss_kernel<<<C_DIM, BLOCK, 0, stream>>>(preds, targets, ws);
    mean_reduce_kernel<<<1, BLOCK, 0, stream>>>(ws, out);
}

// Round 2
// 371.693 us; speedup vs baseline: 1.0248x; 1.0248x over previous
//
#include <hip/hip_runtime.h>

#define C_DIM 8192
#define BLOCK 256
#define PER_THREAD 32              // C_DIM / BLOCK
#define NVEC 8                     // PER_THREAD / 4 float4 loads per thread

// strict ordering matching jax.lax.top_k: higher value wins, ties -> lower index
__device__ __forceinline__ bool better(float a, int ia, float b, int ib) {
    return (a > b) || (a == b && ia < ib);
}

// insert (x,j) into descending-sorted 4-list (epilogue only: runs 16x per block)
__device__ __forceinline__ void insert4(float v[4], int id[4], float x, int j) {
    if (better(x, j, v[3], id[3])) {
        v[3] = x; id[3] = j;
        if (better(v[3], id[3], v[2], id[2])) { float tv = v[2]; int ti = id[2]; v[2] = v[3]; id[2] = id[3]; v[3] = tv; id[3] = ti; }
        if (better(v[2], id[2], v[1], id[1])) { float tv = v[1]; int ti = id[1]; v[1] = v[2]; id[1] = id[2]; v[2] = tv; id[2] = ti; }
        if (better(v[1], id[1], v[0], id[0])) { float tv = v[0]; int ti = id[0]; v[0] = v[1]; id[0] = id[1]; v[1] = tv; id[1] = ti; }
    }
}

// register slot (0..31) -> global column index for this thread
__device__ __forceinline__ int slot2col(int tid, int s) {
    return ((s >> 2) * BLOCK + tid) * 4 + (s & 3);
}

__global__ __launch_bounds__(BLOCK) void row_loss_kernel(const float* __restrict__ preds,
                                                         const int* __restrict__ targets,
                                                         float* __restrict__ row_loss) {
    const int row  = blockIdx.x;
    const int tid  = threadIdx.x;
    const int lane = tid & 63;
    const int wid  = tid >> 6;

    const float*  base = preds + (size_t)row * C_DIM;
    const float4* rp   = (const float4*)base;

    __shared__ float s_s[4], s_l[4];
    __shared__ float s_tv[16];   // 4 waves x top-4 values
    __shared__ int   s_ti[16];   // 4 waves x top-4 global column indices

    float xgt = 0.0f;
    if (tid == 0) xgt = base[targets[row]];   // single gather replaces per-elem compare

    // ---- Pass 1: stream row into registers; sum + local argmax (3 ops/elem) ----
    float r[PER_THREAD];
    float lsum = 0.0f;
    float lv = -INFINITY;        // local best value
    int   ls = 0;                // local best slot

#pragma unroll
    for (int v = 0; v < NVEC; ++v) {
        float4 f = rp[v * BLOCK + tid];
        float e0 = f.x, e1 = f.y, e2 = f.z, e3 = f.w;
        r[v * 4 + 0] = e0; r[v * 4 + 1] = e1; r[v * 4 + 2] = e2; r[v * 4 + 3] = e3;
        lsum += (e0 + e1) + (e2 + e3);
        // strict > scanning in slot order keeps lowest index on ties
        if (e0 > lv) { lv = e0; ls = v * 4 + 0; }
        if (e1 > lv) { lv = e1; ls = v * 4 + 1; }
        if (e2 > lv) { lv = e2; ls = v * 4 + 2; }
        if (e3 > lv) { lv = e3; ls = v * 4 + 3; }
    }

    // wave sum reduction
    float wsum = lsum;
#pragma unroll
    for (int o = 32; o; o >>= 1) wsum += __shfl_xor(wsum, o);
    if (lane == 0) s_s[wid] = wsum;

    // ---- Wave-level top-4: 4 rounds of argmax-butterfly + owner rescan ----
    int lj = slot2col(tid, ls);
    float wtv[4]; int wti[4];
#pragma unroll
    for (int round = 0; round < 4; ++round) {
        float rv = lv; int ri = lj;
#pragma unroll
        for (int o = 32; o; o >>= 1) {
            float ov = __shfl_xor(rv, o);
            int   oi = __shfl_xor(ri, o);
            if (better(ov, oi, rv, ri)) { rv = ov; ri = oi; }
        }
        wtv[round] = rv; wti[round] = ri;      // all lanes know the wave winner
        if (lj == ri) {                        // exactly one owner lane
            r[ls] = -INFINITY;                 // mask it out; exp pass gives 0 here
            lv = r[0]; ls = 0;
#pragma unroll
            for (int k = 1; k < PER_THREAD; ++k)
                if (r[k] > lv) { lv = r[k]; ls = k; }
            lj = slot2col(tid, ls);
        }
    }
    if (lane == 0) {
#pragma unroll
        for (int k = 0; k < 4; ++k) { s_tv[wid * 4 + k] = wtv[k]; s_ti[wid * 4 + k] = wti[k]; }
    }
    __syncthreads();

    // block max = max of the 4 wave round-0 winners
    const float m = fmaxf(fmaxf(s_tv[0], s_tv[4]), fmaxf(s_tv[8], s_tv[12]));

    // ---- Pass 2: sum of exp(x - m) from registers (masked slots contribute 0) ----
    float le = 0.0f;
#pragma unroll
    for (int k = 0; k < PER_THREAD; ++k) le += __expf(r[k] - m);
#pragma unroll
    for (int o = 32; o; o >>= 1) le += __shfl_xor(le, o);
    if (lane == 0) s_l[wid] = le;
    __syncthreads();

    if (tid == 0) {
        const float Sx = s_s[0] + s_s[1] + s_s[2] + s_s[3];
        float l = s_l[0] + s_l[1] + s_l[2] + s_l[3];
        // add back the 16 wave-masked elements' exp contributions (all sit in LDS)
#pragma unroll
        for (int k = 0; k < 16; ++k) l += __expf(s_tv[k] - m);

        // merge 4 wave top-4 lists -> block top-4
        float fv[4] = { -INFINITY, -INFINITY, -INFINITY, -INFINITY };
        int   fi[4] = { 0x7FFFFFFF, 0x7FFFFFFF, 0x7FFFFFFF, 0x7FFFFFFF };
#pragma unroll
        for (int k = 0; k < 16; ++k) insert4(fv, fi, s_tv[k], s_ti[k]);

        const float logZ  = m + __logf(l);
        const float lp_gt = xgt - logZ;

        // first 3 non-gt entries of top-4 (gt compared against row index, per reference)
        float skip_x = 0.0f; int cnt = 0;
#pragma unroll
        for (int k = 0; k < 4; ++k)
            if (fi[k] != row && cnt < 3) { skip_x += fv[k]; ++cnt; }

        const float S_lp    = Sx - (float)C_DIM * logZ;
        const float skip_lp = skip_x - 3.0f * logZ;
        const float eps     = 0.1f / (float)(C_DIM - 1);

        row_loss[row] = -(0.9f * lp_gt + eps * (S_lp - lp_gt - skip_lp));
    }
}

__global__ __launch_bounds__(BLOCK) void mean_reduce_kernel(const float* __restrict__ row_loss,
                                                            float* __restrict__ out) {
    const int tid = threadIdx.x;
    float s = 0.0f;
    for (int i = tid; i < C_DIM; i += BLOCK) s += row_loss[i];
#pragma unroll
    for (int o = 32; o; o >>= 1) s += __shfl_xor(s, o);
    __shared__ float sm[4];
    if ((tid & 63) == 0) sm[tid >> 6] = s;
    __syncthreads();
    if (tid == 0) out[0] = (sm[0] + sm[1] + sm[2] + sm[3]) / (float)C_DIM;
}

extern "C" void kernel_launch(void* const* d_in, const int* in_sizes, int n_in,
                              void* d_out, int out_size, void* d_ws, size_t ws_size,
                              hipStream_t stream) {
    const float* preds   = (const float*)d_in[0];
    const int*   targets = (const int*)d_in[1];
    float*       out     = (float*)d_out;
    float*       ws      = (float*)d_ws;   // 8192 floats of row losses

    row_loss_kernel<<<C_DIM, BLOCK, 0, stream>>>(preds, targets, ws);
    mean_reduce_kernel<<<1, BLOCK, 0, stream>>>(ws, out);
}

// Round 3
// 361.446 us; speedup vs baseline: 1.0539x; 1.0284x over previous
//
#include <hip/hip_runtime.h>

#define C_DIM 8192
#define BLOCK 256
#define PER_THREAD 32              // C_DIM / BLOCK
#define NVEC 8                     // PER_THREAD / 4 float4 loads per thread

// value-only descending insert into 4-list (epilogue, 16x per block)
__device__ __forceinline__ void insert4(float v[4], int id[4], float x, int j) {
    if (x > v[3]) {
        v[3] = x; id[3] = j;
        if (v[3] > v[2]) { float tv = v[2]; int ti = id[2]; v[2] = v[3]; id[2] = id[3]; v[3] = tv; id[3] = ti; }
        if (v[2] > v[1]) { float tv = v[1]; int ti = id[1]; v[1] = v[2]; id[1] = id[2]; v[2] = tv; id[2] = ti; }
        if (v[1] > v[0]) { float tv = v[0]; int ti = id[0]; v[0] = v[1]; id[0] = id[1]; v[1] = tv; id[1] = ti; }
    }
}

__global__ __launch_bounds__(BLOCK) void row_loss_kernel(const float* __restrict__ preds,
                                                         const int* __restrict__ targets,
                                                         float* __restrict__ row_loss) {
    const int row  = blockIdx.x;
    const int tid  = threadIdx.x;
    const int lane = tid & 63;
    const int wid  = tid >> 6;

    const float*  base = preds + (size_t)row * C_DIM;
    const float4* rp   = (const float4*)base;

    __shared__ float s_s[4], s_l[4];
    __shared__ float s_tv[16];   // 4 waves x top-4 values
    __shared__ int   s_ti[16];   // 4 waves x top-4 global column indices

    float xgt = 0.0f;
    if (tid == 0) xgt = base[targets[row]];   // single gather for the gt logit

    // ---- Single streaming pass: sum, exp-sum (no max shift: |x|<~6), lane max ----
    float r[PER_THREAD];
    float lsum = 0.0f, lexp = 0.0f;
    float lv = -INFINITY;

#pragma unroll
    for (int v = 0; v < NVEC; ++v) {
        float4 f = rp[v * BLOCK + tid];
        r[v * 4 + 0] = f.x; r[v * 4 + 1] = f.y; r[v * 4 + 2] = f.z; r[v * 4 + 3] = f.w;
        lsum += (f.x + f.y) + (f.z + f.w);
        lexp += (__expf(f.x) + __expf(f.y)) + (__expf(f.z) + __expf(f.w));
        lv = fmaxf(fmaxf(lv, fmaxf(f.x, f.y)), fmaxf(f.z, f.w));
    }

    // wave butterflies for sum and exp-sum
    float wsum = lsum, wexp = lexp;
#pragma unroll
    for (int o = 32; o; o >>= 1) {
        wsum += __shfl_xor(wsum, o);
        wexp += __shfl_xor(wexp, o);
    }

    // ---- Wave top-4: value-only max butterfly + ballot-elected owner rescan ----
    // All register indexing below is static (fully unrolled) -> stays in VGPRs.
    float wtv[4]; int wti[4];
#pragma unroll
    for (int round = 0; round < 4; ++round) {
        float rv = lv;
#pragma unroll
        for (int o = 32; o; o >>= 1) rv = fmaxf(rv, __shfl_xor(rv, o));
        unsigned long long own = __ballot(lv == rv);   // fmax returns an operand bit-exactly
        int owner = __ffsll((long long)own) - 1;
        int gcol = 0;
        if (lane == owner) {
            // find first slot holding rv, kill it, recompute lane max
            bool killed = false;
            int slot = 0;
#pragma unroll
            for (int k = 0; k < PER_THREAD; ++k) {
                bool hit = (!killed) && (r[k] == rv);
                if (hit) { slot = k; killed = true; }
            }
#pragma unroll
            for (int k = 0; k < PER_THREAD; ++k)
                if (k == slot) r[k] = -INFINITY;       // static index select chain
            gcol = ((slot >> 2) * BLOCK + tid) * 4 + (slot & 3);
            lv = r[0];
#pragma unroll
            for (int k = 1; k < PER_THREAD; ++k) lv = fmaxf(lv, r[k]);
        }
        gcol = __shfl(gcol, owner);
        wtv[round] = rv; wti[round] = gcol;
    }

    if (lane == 0) {
        s_s[wid] = wsum;
        s_l[wid] = wexp;
#pragma unroll
        for (int k = 0; k < 4; ++k) { s_tv[wid * 4 + k] = wtv[k]; s_ti[wid * 4 + k] = wti[k]; }
    }
    __syncthreads();

    if (tid == 0) {
        const float Sx = (s_s[0] + s_s[1]) + (s_s[2] + s_s[3]);
        const float l  = (s_l[0] + s_l[1]) + (s_l[2] + s_l[3]);

        // merge 4 wave top-4 lists -> block top-4
        float fv[4] = { -INFINITY, -INFINITY, -INFINITY, -INFINITY };
        int   fi[4] = { 0, 0, 0, 0 };
#pragma unroll
        for (int k = 0; k < 16; ++k) insert4(fv, fi, s_tv[k], s_ti[k]);

        const float logZ  = __logf(l);
        const float lp_gt = xgt - logZ;

        // first 3 non-gt of top-4 (gt excluded by row index, matching the reference)
        float skip_x = 0.0f; int cnt = 0;
#pragma unroll
        for (int k = 0; k < 4; ++k)
            if (fi[k] != row && cnt < 3) { skip_x += fv[k]; ++cnt; }

        const float S_lp    = Sx - (float)C_DIM * logZ;
        const float skip_lp = skip_x - 3.0f * logZ;
        const float eps     = 0.1f / (float)(C_DIM - 1);

        row_loss[row] = -(0.9f * lp_gt + eps * (S_lp - lp_gt - skip_lp));
    }
}

__global__ __launch_bounds__(BLOCK) void mean_reduce_kernel(const float* __restrict__ row_loss,
                                                            float* __restrict__ out) {
    const int tid = threadIdx.x;
    const float4* rl = (const float4*)row_loss;
    float s = 0.0f;
#pragma unroll
    for (int v = 0; v < 8; ++v) {
        float4 f = rl[v * BLOCK + tid];
        s += (f.x + f.y) + (f.z + f.w);
    }
#pragma unroll
    for (int o = 32; o; o >>= 1) s += __shfl_xor(s, o);
    __shared__ float sm[4];
    if ((tid & 63) == 0) sm[tid >> 6] = s;
    __syncthreads();
    if (tid == 0) out[0] = ((sm[0] + sm[1]) + (sm[2] + sm[3])) / (float)C_DIM;
}

extern "C" void kernel_launch(void* const* d_in, const int* in_sizes, int n_in,
                              void* d_out, int out_size, void* d_ws, size_t ws_size,
                              hipStream_t stream) {
    const float* preds   = (const float*)d_in[0];
    const int*   targets = (const int*)d_in[1];
    float*       out     = (float*)d_out;
    float*       ws      = (float*)d_ws;   // 8192 floats of row losses

    row_loss_kernel<<<C_DIM, BLOCK, 0, stream>>>(preds, targets, ws);
    mean_reduce_kernel<<<1, BLOCK, 0, stream>>>(ws, out);
}